// Round 3
// baseline (613.274 us; speedup 1.0000x reference)
//
#include <hip/hip_runtime.h>
#include <math.h>

// HPool: z[n,c] = sum_hw tanh(x[n,c,hw]) * coeff[c, bin(x[n,c,hw])]
// bins = linspace(global_min, global_max, 33), searchsorted-right, clip [0,31].
//
// SINGLE-READ structure. x is read from HBM exactly once:
//   kernel A (one block per (n,c)): read 64 KiB slice; per value accumulate
//     tanh(v) into a FIXED-EDGE fine histogram (1024 bins over [-8,8]) held in
//     LDS via ds_add_f32; also exact block min/max. Write hist (4 KiB) + mm.
//   kernel B (one block per (n,c)): redundantly reduce the 4096 min/max
//     partials (L2-hot), derive coarse edges, map each fine bin to a coarse
//     bin; a fine bin straddling a coarse edge splits its sum linearly by the
//     overlap fraction. Reduce -> out[nc].
// Fine-bin split error ~0.2 per edge (95 values * tanh' * w/8) -- negligible
// vs threshold 47.68 (absmax was 4.0 with exact per-value binning: fp64-ref
// dominates).
//
// Shapes: N=64, C=64, HW=16384, BINS=32. x = 256 MiB fp32.

constexpr int BT    = 256;
constexpr int BINS  = 32;
constexpr int FB    = 1024;                 // fine bins
constexpr float FSCALE = 64.0f;             // bins per unit value
constexpr float FINV   = 1.0f / FSCALE;     // fine bin width
constexpr float FOFF   = 512.0f;            // q = v*FSCALE + FOFF  (range [-8,8))

__device__ __forceinline__ float wave_min(float v) {
#pragma unroll
    for (int off = 32; off > 0; off >>= 1) v = fminf(v, __shfl_down(v, off, 64));
    return v;
}
__device__ __forceinline__ float wave_max(float v) {
#pragma unroll
    for (int off = 32; off > 0; off >>= 1) v = fmaxf(v, __shfl_down(v, off, 64));
    return v;
}
__device__ __forceinline__ float wave_sum(float v) {
#pragma unroll
    for (int off = 32; off > 0; off >>= 1) v += __shfl_down(v, off, 64);
    return v;
}

// -------- kernel A: one pass over x -> fine hist + min/max partials --------
__global__ __launch_bounds__(BT) void fine_hist(
    const float* __restrict__ x, float* __restrict__ hist_g,
    float2* __restrict__ pmm, int hw4) {
    __shared__ float s_hist[FB];
    __shared__ float smin[4], smax[4];
    const int t  = threadIdx.x;
    const int nc = blockIdx.x;
#pragma unroll
    for (int k = t; k < FB; k += BT) s_hist[k] = 0.0f;
    __syncthreads();

    const float4* base = (const float4*)x + (size_t)nc * hw4;
    float vmin = INFINITY, vmax = -INFINITY;
    const int iters = hw4 / BT;             // 16 for the fixed shapes

    auto one = [&](float v) {
        vmin = fminf(vmin, v);
        vmax = fmaxf(vmax, v);
        int q = (int)fmaf(v, FSCALE, FOFF); // trunc; v>=-8 so q>=0
        q = q < 0 ? 0 : (q > FB - 1 ? FB - 1 : q);
        float e  = __expf(2.0f * v);        // |2v| < ~12, no overflow
        float th = fmaf(-2.0f, __frcp_rn(e + 1.0f), 1.0f);   // tanh(v)
        atomicAdd(&s_hist[q], th);          // ds_add_f32
    };

#pragma unroll 4
    for (int k = 0; k < iters; ++k) {
        float4 v = base[t + BT * k];
        one(v.x); one(v.y); one(v.z); one(v.w);
    }

    const int lane = t & 63, wave = t >> 6;
    vmin = wave_min(vmin);
    vmax = wave_max(vmax);
    if (lane == 0) { smin[wave] = vmin; smax[wave] = vmax; }
    __syncthreads();
    if (t == 0) {
        pmm[nc] = make_float2(
            fminf(fminf(smin[0], smin[1]), fminf(smin[2], smin[3])),
            fmaxf(fmaxf(smax[0], smax[1]), fmaxf(smax[2], smax[3])));
    }
    // write back the block's fine histogram (4 KiB, coalesced)
    float* hg = hist_g + (size_t)nc * FB;
#pragma unroll
    for (int k = t; k < FB; k += BT) hg[k] = s_hist[k];
}

// -------- kernel B: fine hist -> coarse coeff-weighted sum --------
__global__ __launch_bounds__(BT) void coarse_map(
    const float* __restrict__ hist_g, const float* __restrict__ coeff,
    const float2* __restrict__ pmm, float* __restrict__ out,
    int C, int nc_total) {
    __shared__ float s_coeff[BINS];
    __shared__ float smin[4], smax[4], s_red[4];
    __shared__ float s_par[3];              // m, step, inv_step
    const int t    = threadIdx.x;
    const int nc   = blockIdx.x;
    const int c    = nc % C;
    const int lane = t & 63, wave = t >> 6;

    // redundant global min/max reduce (32 KiB, L2-hot)
    float vmin = INFINITY, vmax = -INFINITY;
#pragma unroll
    for (int k = t; k < nc_total; k += BT) {
        float2 mm = pmm[k];
        vmin = fminf(vmin, mm.x);
        vmax = fmaxf(vmax, mm.y);
    }
    vmin = wave_min(vmin);
    vmax = wave_max(vmax);
    if (lane == 0) { smin[wave] = vmin; smax[wave] = vmax; }
    if (t < BINS) s_coeff[t] = coeff[c * BINS + t];
    __syncthreads();
    if (t == 0) {
        float m = fminf(fminf(smin[0], smin[1]), fminf(smin[2], smin[3]));
        float M = fmaxf(fmaxf(smax[0], smax[1]), fmaxf(smax[2], smax[3]));
        float step = (M - m) / (float)BINS;
        s_par[0] = m;
        s_par[1] = step;
        s_par[2] = 1.0f / step;
    }
    __syncthreads();
    const float m = s_par[0], step = s_par[1], inv = s_par[2];

    const float* hg = hist_g + (size_t)nc * FB;
    float acc = 0.0f;
#pragma unroll
    for (int q = t; q < FB; q += BT) {
        float s = hg[q];
        if (s != 0.0f) {
            float lo = fmaf((float)q, FINV, -8.0f);
            float hi = lo + FINV;
            int bl = (int)floorf((lo - m) * inv);
            int bh = (int)floorf((hi - m) * inv);
            bl = bl < 0 ? 0 : (bl > BINS - 1 ? BINS - 1 : bl);
            bh = bh < 0 ? 0 : (bh > BINS - 1 ? BINS - 1 : bh);
            if (bl == bh) {
                acc += s * s_coeff[bl];
            } else {
                float edge = fmaf((float)bh, step, m);
                float f = (edge - lo) * FSCALE;      // fraction of bin below edge
                f = f < 0.0f ? 0.0f : (f > 1.0f ? 1.0f : f);
                acc += s * fmaf(f, s_coeff[bl] - s_coeff[bh], s_coeff[bh]);
            }
        }
    }
    acc = wave_sum(acc);
    if (lane == 0) s_red[wave] = acc;
    __syncthreads();
    if (t == 0) out[nc] = s_red[0] + s_red[1] + s_red[2] + s_red[3];
}

extern "C" void kernel_launch(void* const* d_in, const int* in_sizes, int n_in,
                              void* d_out, int out_size, void* d_ws, size_t ws_size,
                              hipStream_t stream) {
    const float* x     = (const float*)d_in[0];
    const float* coeff = (const float*)d_in[1];
    float* out = (float*)d_out;

    const int total = in_sizes[0];          // 67,108,864
    const int C     = in_sizes[1] / BINS;   // 64
    const int NC    = out_size;             // 4096
    const int hw4   = total / NC / 4;       // 4096 float4 per (n,c)

    // ws layout: [0, NC) float2 pmm | then NC*FB floats hist (16 MiB)
    float2* pmm    = (float2*)d_ws;
    float*  hist_g = (float*)d_ws + 2 * NC;

    fine_hist<<<NC, BT, 0, stream>>>(x, hist_g, pmm, hw4);
    coarse_map<<<NC, BT, 0, stream>>>(hist_g, coeff, pmm, out, C, NC);
}

// Round 4
// 611.727 us; speedup vs baseline: 1.0025x; 1.0025x over previous
//
#include <hip/hip_runtime.h>
#include <math.h>

// HPool: z[n,c] = sum_hw tanh(x[n,c,hw]) * coeff[c, bin(x[n,c,hw])]
// bins = linspace(global_min, global_max, 33), searchsorted-right, clip [0,31].
//
// SINGLE-READ structure (x read from HBM/L3 exactly once):
//   kernel A (one block per (n,c)): read 64 KiB slice; per value accumulate
//     tanh(v) into a FIXED-EDGE fine histogram (1024 bins over [-8,8]) in LDS.
//     R3 lesson: plain atomicAdd(float*) on LDS compiles to a CAS loop
//     (~200 cyc/op, latency-bound -> 347 us). Use unsafeAtomicAdd -> native
//     ds_add_f32 (fire-and-forget, no return dependency).
//   kernel B (one block per (n,c)): reduce min/max partials (L2-hot), derive
//     coarse edges, map fine bins -> coarse bins with linear split of
//     straddling bins. absmax 16 vs threshold 47.68 with this scheme (R3).
//
// Shapes: N=64, C=64, HW=16384, BINS=32. x = 256 MiB fp32.

constexpr int BT    = 256;
constexpr int BINS  = 32;
constexpr int FB    = 1024;                 // fine bins
constexpr float FSCALE = 64.0f;             // bins per unit value
constexpr float FINV   = 1.0f / FSCALE;     // fine bin width
constexpr float FOFF   = 512.0f;            // q = v*FSCALE + FOFF  (range [-8,8))

__device__ __forceinline__ float wave_min(float v) {
#pragma unroll
    for (int off = 32; off > 0; off >>= 1) v = fminf(v, __shfl_down(v, off, 64));
    return v;
}
__device__ __forceinline__ float wave_max(float v) {
#pragma unroll
    for (int off = 32; off > 0; off >>= 1) v = fmaxf(v, __shfl_down(v, off, 64));
    return v;
}
__device__ __forceinline__ float wave_sum(float v) {
#pragma unroll
    for (int off = 32; off > 0; off >>= 1) v += __shfl_down(v, off, 64);
    return v;
}

// -------- kernel A: one pass over x -> fine hist + min/max partials --------
__global__ __launch_bounds__(BT) void fine_hist(
    const float* __restrict__ x, float* __restrict__ hist_g,
    float2* __restrict__ pmm, int hw4) {
    __shared__ float s_hist[FB];
    __shared__ float smin[4], smax[4];
    const int t  = threadIdx.x;
    const int nc = blockIdx.x;
#pragma unroll
    for (int k = t; k < FB; k += BT) s_hist[k] = 0.0f;
    __syncthreads();

    const float4* base = (const float4*)x + (size_t)nc * hw4;
    float vmin = INFINITY, vmax = -INFINITY;
    const int iters = hw4 / BT;             // 16 for the fixed shapes

    auto one = [&](float v) {
        vmin = fminf(vmin, v);
        vmax = fmaxf(vmax, v);
        int q = (int)fmaf(v, FSCALE, FOFF); // trunc; v>=-8 so q>=0
        q = q < 0 ? 0 : (q > FB - 1 ? FB - 1 : q);
        float e  = __expf(2.0f * v);        // |2v| < ~12, no overflow
        float th = fmaf(-2.0f, __frcp_rn(e + 1.0f), 1.0f);   // tanh(v)
        unsafeAtomicAdd(&s_hist[q], th);    // native ds_add_f32, no CAS loop
    };

#pragma unroll 4
    for (int k = 0; k < iters; ++k) {
        float4 v = base[t + BT * k];
        one(v.x); one(v.y); one(v.z); one(v.w);
    }

    const int lane = t & 63, wave = t >> 6;
    vmin = wave_min(vmin);
    vmax = wave_max(vmax);
    if (lane == 0) { smin[wave] = vmin; smax[wave] = vmax; }
    __syncthreads();
    if (t == 0) {
        pmm[nc] = make_float2(
            fminf(fminf(smin[0], smin[1]), fminf(smin[2], smin[3])),
            fmaxf(fmaxf(smax[0], smax[1]), fmaxf(smax[2], smax[3])));
    }
    // write back the block's fine histogram (4 KiB, coalesced)
    float* hg = hist_g + (size_t)nc * FB;
#pragma unroll
    for (int k = t; k < FB; k += BT) hg[k] = s_hist[k];
}

// -------- kernel B: fine hist -> coarse coeff-weighted sum --------
__global__ __launch_bounds__(BT) void coarse_map(
    const float* __restrict__ hist_g, const float* __restrict__ coeff,
    const float2* __restrict__ pmm, float* __restrict__ out,
    int C, int nc_total) {
    __shared__ float s_coeff[BINS];
    __shared__ float smin[4], smax[4], s_red[4];
    __shared__ float s_par[3];              // m, step, inv_step
    const int t    = threadIdx.x;
    const int nc   = blockIdx.x;
    const int c    = nc % C;
    const int lane = t & 63, wave = t >> 6;

    // redundant global min/max reduce (32 KiB, L2-hot)
    float vmin = INFINITY, vmax = -INFINITY;
#pragma unroll
    for (int k = t; k < nc_total; k += BT) {
        float2 mm = pmm[k];
        vmin = fminf(vmin, mm.x);
        vmax = fmaxf(vmax, mm.y);
    }
    vmin = wave_min(vmin);
    vmax = wave_max(vmax);
    if (lane == 0) { smin[wave] = vmin; smax[wave] = vmax; }
    if (t < BINS) s_coeff[t] = coeff[c * BINS + t];
    __syncthreads();
    if (t == 0) {
        float m = fminf(fminf(smin[0], smin[1]), fminf(smin[2], smin[3]));
        float M = fmaxf(fmaxf(smax[0], smax[1]), fmaxf(smax[2], smax[3]));
        float step = (M - m) / (float)BINS;
        s_par[0] = m;
        s_par[1] = step;
        s_par[2] = 1.0f / step;
    }
    __syncthreads();
    const float m = s_par[0], step = s_par[1], inv = s_par[2];

    const float* hg = hist_g + (size_t)nc * FB;
    float acc = 0.0f;
#pragma unroll
    for (int q = t; q < FB; q += BT) {
        float s = hg[q];
        if (s != 0.0f) {
            float lo = fmaf((float)q, FINV, -8.0f);
            float hi = lo + FINV;
            int bl = (int)floorf((lo - m) * inv);
            int bh = (int)floorf((hi - m) * inv);
            bl = bl < 0 ? 0 : (bl > BINS - 1 ? BINS - 1 : bl);
            bh = bh < 0 ? 0 : (bh > BINS - 1 ? BINS - 1 : bh);
            if (bl == bh) {
                acc += s * s_coeff[bl];
            } else {
                float edge = fmaf((float)bh, step, m);
                float f = (edge - lo) * FSCALE;      // fraction of bin below edge
                f = f < 0.0f ? 0.0f : (f > 1.0f ? 1.0f : f);
                acc += s * fmaf(f, s_coeff[bl] - s_coeff[bh], s_coeff[bh]);
            }
        }
    }
    acc = wave_sum(acc);
    if (lane == 0) s_red[wave] = acc;
    __syncthreads();
    if (t == 0) out[nc] = s_red[0] + s_red[1] + s_red[2] + s_red[3];
}

extern "C" void kernel_launch(void* const* d_in, const int* in_sizes, int n_in,
                              void* d_out, int out_size, void* d_ws, size_t ws_size,
                              hipStream_t stream) {
    const float* x     = (const float*)d_in[0];
    const float* coeff = (const float*)d_in[1];
    float* out = (float*)d_out;

    const int total = in_sizes[0];          // 67,108,864
    const int C     = in_sizes[1] / BINS;   // 64
    const int NC    = out_size;             // 4096
    const int hw4   = total / NC / 4;       // 4096 float4 per (n,c)

    // ws layout: [0, NC) float2 pmm | then NC*FB floats hist (16 MiB)
    float2* pmm    = (float2*)d_ws;
    float*  hist_g = (float*)d_ws + 2 * NC;

    fine_hist<<<NC, BT, 0, stream>>>(x, hist_g, pmm, hw4);
    coarse_map<<<NC, BT, 0, stream>>>(hist_g, coeff, pmm, out, C, NC);
}

// Round 5
// 403.855 us; speedup vs baseline: 1.5186x; 1.5147x over previous
//
#include <hip/hip_runtime.h>
#include <math.h>

// HPool: z[n,c] = sum_hw tanh(x[n,c,hw]) * coeff[c, bin(x[n,c,hw])]
// bins = linspace(global_min, global_max, 33), searchsorted-right, clip [0,31].
//
// R3/R4 lesson: scattered LDS atomics serialize per-lane (~200 cyc per wave op
// on the shared DS pipe) -> fine-histogram design is dead. R5 returns to the
// direct form with ZERO per-element LDS traffic except one ds_bpermute:
//   pass1: 2048-block grid-stride min/max partials -> pmm (16 KiB ws)
//   pass2: one block per (n,c). Prologue: every block reduces pmm (L2-hot)
//          to global min/max, derives inv_step. Each thread preloads
//          cf = coeff[c*32 + (lane&31)] into a register. Main loop per value:
//          idx = min((int)((v-min)*inv_step), 31); w = __shfl(cf, idx)
//          (ds_bpermute_b32: conflict-free crossbar, no serialization);
//          acc += tanh(v)*w. tanh via __expf + __frcp_rn (~2 ulp).
//
// Shapes: N=64, C=64, HW=16384, BINS=32. x = 256 MiB fp32 (== L3 size;
// pass1 pre-warms L3 for pass2 -> pass2 HBM fetch ~halved).

constexpr int NB1  = 2048;   // pass-1 blocks
constexpr int BT   = 256;    // threads/block
constexpr int BINS = 32;

__device__ __forceinline__ float wave_min(float v) {
#pragma unroll
    for (int off = 32; off > 0; off >>= 1) v = fminf(v, __shfl_down(v, off, 64));
    return v;
}
__device__ __forceinline__ float wave_max(float v) {
#pragma unroll
    for (int off = 32; off > 0; off >>= 1) v = fmaxf(v, __shfl_down(v, off, 64));
    return v;
}
__device__ __forceinline__ float wave_sum(float v) {
#pragma unroll
    for (int off = 32; off > 0; off >>= 1) v += __shfl_down(v, off, 64);
    return v;
}

// ---------------- pass 1: per-block min/max partials ----------------
__global__ __launch_bounds__(BT) void minmax_partial(
    const float4* __restrict__ x4, int n4, float2* __restrict__ pmm) {
    float vmin = INFINITY, vmax = -INFINITY;
    const int stride = NB1 * BT;
    const int i0     = blockIdx.x * BT + threadIdx.x;
    const int iters  = n4 / stride;           // 32 for the fixed shapes
#pragma unroll 4
    for (int k = 0; k < iters; ++k) {
        float4 v = x4[i0 + k * stride];
        vmin = fminf(vmin, fminf(fminf(v.x, v.y), fminf(v.z, v.w)));
        vmax = fmaxf(vmax, fmaxf(fmaxf(v.x, v.y), fmaxf(v.z, v.w)));
    }
    const int r = i0 + iters * stride;        // tail guard (robust to shape change)
    if (r < n4) {
        float4 v = x4[r];
        vmin = fminf(vmin, fminf(fminf(v.x, v.y), fminf(v.z, v.w)));
        vmax = fmaxf(vmax, fmaxf(fmaxf(v.x, v.y), fmaxf(v.z, v.w)));
    }
    __shared__ float smin[4], smax[4];
    const int lane = threadIdx.x & 63, wave = threadIdx.x >> 6;
    vmin = wave_min(vmin);
    vmax = wave_max(vmax);
    if (lane == 0) { smin[wave] = vmin; smax[wave] = vmax; }
    __syncthreads();
    if (threadIdx.x == 0) {
        pmm[blockIdx.x] = make_float2(
            fminf(fminf(smin[0], smin[1]), fminf(smin[2], smin[3])),
            fmaxf(fmaxf(smax[0], smax[1]), fmaxf(smax[2], smax[3])));
    }
}

// ---------------- pass 2: fused reduce + main kernel ----------------
__global__ __launch_bounds__(BT) void hpool_main(
    const float* __restrict__ x, const float* __restrict__ coeff,
    const float2* __restrict__ pmm, float* __restrict__ out,
    int C, int hw4) {
    __shared__ float smin[4], smax[4], s_red[4];
    __shared__ float s_par[2];                 // inv_step, -min*inv_step
    const int t    = threadIdx.x;
    const int nc   = blockIdx.x;
    const int c    = nc % C;
    const int lane = t & 63, wave = t >> 6;

    // per-lane coeff fragment: lane j holds coeff[c, j&31] (wave-replicated)
    const float cf = coeff[c * BINS + (lane & (BINS - 1))];

    // prologue: every block reduces the 2048 partials (L2-hot, 16 KiB)
    float vmin = INFINITY, vmax = -INFINITY;
#pragma unroll
    for (int k = t; k < NB1; k += BT) {
        float2 mm = pmm[k];
        vmin = fminf(vmin, mm.x);
        vmax = fmaxf(vmax, mm.y);
    }
    vmin = wave_min(vmin);
    vmax = wave_max(vmax);
    if (lane == 0) { smin[wave] = vmin; smax[wave] = vmax; }
    __syncthreads();
    if (t == 0) {
        float m = fminf(fminf(smin[0], smin[1]), fminf(smin[2], smin[3]));
        float M = fmaxf(fmaxf(smax[0], smax[1]), fmaxf(smax[2], smax[3]));
        float step = (M - m) / (float)BINS;
        float inv  = 1.0f / step;
        s_par[0] = inv;
        s_par[1] = -m * inv;
    }
    __syncthreads();
    const float inv_step = s_par[0];
    const float nmi      = s_par[1];

    const float4* base = (const float4*)x + (size_t)nc * hw4;
    float acc0 = 0.0f, acc1 = 0.0f;
    const int iters = hw4 / BT;                // 16 for the fixed shapes

    auto contrib = [&](float v) -> float {
        float sc  = fmaf(v, inv_step, nmi);    // bin-space position, >= -1ulp
        int   idx = (int)sc;                   // trunc: (-1,0) -> 0
        idx = idx > BINS - 1 ? BINS - 1 : idx;
        float w   = __shfl(cf, idx, 64);       // ds_bpermute_b32: conflict-free
        float e   = __expf(2.0f * v);          // |2v| < ~12, no overflow
        float th  = fmaf(-2.0f, __frcp_rn(e + 1.0f), 1.0f);  // tanh(v)
        return th * w;
    };

#pragma unroll 4
    for (int k = 0; k < iters; ++k) {
        float4 v = base[t + BT * k];
        acc0 += contrib(v.x);
        acc1 += contrib(v.y);
        acc0 += contrib(v.z);
        acc1 += contrib(v.w);
    }
    float acc = wave_sum(acc0 + acc1);
    if (lane == 0) s_red[wave] = acc;
    __syncthreads();
    if (t == 0) out[nc] = s_red[0] + s_red[1] + s_red[2] + s_red[3];
}

extern "C" void kernel_launch(void* const* d_in, const int* in_sizes, int n_in,
                              void* d_out, int out_size, void* d_ws, size_t ws_size,
                              hipStream_t stream) {
    const float* x     = (const float*)d_in[0];
    const float* coeff = (const float*)d_in[1];
    float*  out = (float*)d_out;
    float2* pmm = (float2*)d_ws;               // NB1 float2 = 16 KiB

    const int total = in_sizes[0];             // 67,108,864
    const int n4    = total / 4;
    const int C     = in_sizes[1] / BINS;      // 64
    const int NC    = out_size;                // 4096
    const int hw4   = total / NC / 4;          // 4096 float4 per (n,c)

    minmax_partial<<<NB1, BT, 0, stream>>>((const float4*)x, n4, pmm);
    hpool_main<<<NC, BT, 0, stream>>>(x, coeff, pmm, out, C, hw4);
}

// Round 6
// 402.622 us; speedup vs baseline: 1.5232x; 1.0031x over previous
//
#include <hip/hip_runtime.h>
#include <math.h>

// HPool: z[n,c] = sum_hw tanh(x[n,c,hw]) * coeff[c, bin(x[n,c,hw])]
// bins = linspace(global_min, global_max, 33), searchsorted-right, clip [0,31].
//
// Two-pass direct form (R5) + L3-residency engineering (R6):
//   pass1: 2048 blocks, block b reads CONTIGUOUS slices [2b,2b+1] (128 KiB)
//          -> min/max partial pmm[b]. x == L3 size (256 MiB): at pass1 end,
//          L3 residency is recency-ordered, most-recent = highest address.
//   pass2: one block per (n,c), dispatch REVERSED (nc = NC-1-blockIdx.x):
//          earliest blocks read the most-recently-touched slices -> L3 hits.
//          Prologue: every block reduces pmm (L2-hot). coeff[c,*] lives in a
//          wave register fragment; gather via __shfl (ds_bpermute, conflict-
//          free). tanh via __expf + __frcp_rn (~2 ulp).
//
// Lessons: R3/R4 scattered LDS atomics ~200cyc/wave-op (dead); R5 proved the
// coeff gather is not the bottleneck -- pass2's x re-read is.
//
// Shapes: N=64, C=64, HW=16384, BINS=32. x = 256 MiB fp32.

constexpr int NB1  = 2048;   // pass-1 blocks
constexpr int BT   = 256;    // threads/block
constexpr int BINS = 32;

__device__ __forceinline__ float wave_min(float v) {
#pragma unroll
    for (int off = 32; off > 0; off >>= 1) v = fminf(v, __shfl_down(v, off, 64));
    return v;
}
__device__ __forceinline__ float wave_max(float v) {
#pragma unroll
    for (int off = 32; off > 0; off >>= 1) v = fmaxf(v, __shfl_down(v, off, 64));
    return v;
}
__device__ __forceinline__ float wave_sum(float v) {
#pragma unroll
    for (int off = 32; off > 0; off >>= 1) v += __shfl_down(v, off, 64);
    return v;
}

// ------- pass 1: contiguous per-block min/max partials (recency-clean) -------
__global__ __launch_bounds__(BT) void minmax_partial(
    const float4* __restrict__ x4, int n4, float2* __restrict__ pmm) {
    const int per = n4 / NB1;                 // 8192 float4 per block
    const int i0  = blockIdx.x * per + threadIdx.x;
    const int iters = per / BT;               // 32
    float vmin = INFINITY, vmax = -INFINITY;
#pragma unroll 4
    for (int k = 0; k < iters; ++k) {
        float4 v = x4[i0 + k * BT];
        vmin = fminf(vmin, fminf(fminf(v.x, v.y), fminf(v.z, v.w)));
        vmax = fmaxf(vmax, fmaxf(fmaxf(v.x, v.y), fmaxf(v.z, v.w)));
    }
    // tail (robust to shape changes; empty for the fixed shapes)
    for (int r = NB1 * per + blockIdx.x * BT + threadIdx.x; r < n4; r += NB1 * BT) {
        float4 v = x4[r];
        vmin = fminf(vmin, fminf(fminf(v.x, v.y), fminf(v.z, v.w)));
        vmax = fmaxf(vmax, fmaxf(fmaxf(v.x, v.y), fmaxf(v.z, v.w)));
    }
    __shared__ float smin[4], smax[4];
    const int lane = threadIdx.x & 63, wave = threadIdx.x >> 6;
    vmin = wave_min(vmin);
    vmax = wave_max(vmax);
    if (lane == 0) { smin[wave] = vmin; smax[wave] = vmax; }
    __syncthreads();
    if (threadIdx.x == 0) {
        pmm[blockIdx.x] = make_float2(
            fminf(fminf(smin[0], smin[1]), fminf(smin[2], smin[3])),
            fmaxf(fmaxf(smax[0], smax[1]), fmaxf(smax[2], smax[3])));
    }
}

// ---------------- pass 2: fused reduce + main kernel (reversed) ----------------
__global__ __launch_bounds__(BT) void hpool_main(
    const float* __restrict__ x, const float* __restrict__ coeff,
    const float2* __restrict__ pmm, float* __restrict__ out,
    int C, int hw4, int nc_total) {
    __shared__ float smin[4], smax[4], s_red[4];
    __shared__ float s_par[2];                 // 4*inv_step, 4*(-min*inv_step)
    const int t    = threadIdx.x;
    const int nc   = nc_total - 1 - blockIdx.x;   // reversed: most-recent L3 first
    const int c    = nc % C;
    const int lane = t & 63, wave = t >> 6;

    // per-lane coeff fragment: lane j holds coeff[c, j&31] (wave-replicated)
    const float cf = coeff[c * BINS + (lane & (BINS - 1))];

    // prologue: every block reduces the 2048 partials (L2-hot, 16 KiB)
    float vmin = INFINITY, vmax = -INFINITY;
#pragma unroll
    for (int k = t; k < NB1; k += BT) {
        float2 mm = pmm[k];
        vmin = fminf(vmin, mm.x);
        vmax = fmaxf(vmax, mm.y);
    }
    vmin = wave_min(vmin);
    vmax = wave_max(vmax);
    if (lane == 0) { smin[wave] = vmin; smax[wave] = vmax; }
    __syncthreads();
    if (t == 0) {
        float m = fminf(fminf(smin[0], smin[1]), fminf(smin[2], smin[3]));
        float M = fmaxf(fmaxf(smax[0], smax[1]), fmaxf(smax[2], smax[3]));
        float step = (M - m) / (float)BINS;
        float inv  = 1.0f / step;
        s_par[0] = 4.0f * inv;                 // byte-space binning: idx4 = 4*idx
        s_par[1] = 4.0f * (-m * inv);
    }
    __syncthreads();
    const float inv4 = s_par[0];
    const float nmi4 = s_par[1];

    const float4* base = (const float4*)x + (size_t)nc * hw4;
    float acc0 = 0.0f, acc1 = 0.0f;
    const int iters = hw4 / BT;                // 16 for the fixed shapes

    auto contrib = [&](float v) -> float {
        // byte-space bin: floor(4*sc)&~3 == 4*floor(sc) for sc>=0; feeds
        // ds_bpermute's byte-addressed lane select without an extra shift.
        float sc4 = fmaf(v, inv4, nmi4);
        int  idx4 = (int)sc4;
        idx4 = idx4 > 4 * (BINS - 1) ? 4 * (BINS - 1) : (idx4 & ~3);
        float w   = __builtin_bit_cast(float,
                      __builtin_amdgcn_ds_bpermute(idx4, __builtin_bit_cast(int, cf)));
        float e   = __expf(2.0f * v);          // |2v| < ~12, no overflow
        float th  = fmaf(-2.0f, __frcp_rn(e + 1.0f), 1.0f);  // tanh(v)
        return th * w;
    };

#pragma unroll 4
    for (int k = 0; k < iters; ++k) {
        float4 v = base[t + BT * k];
        acc0 += contrib(v.x);
        acc1 += contrib(v.y);
        acc0 += contrib(v.z);
        acc1 += contrib(v.w);
    }
    float acc = wave_sum(acc0 + acc1);
    if (lane == 0) s_red[wave] = acc;
    __syncthreads();
    if (t == 0) out[nc] = s_red[0] + s_red[1] + s_red[2] + s_red[3];
}

extern "C" void kernel_launch(void* const* d_in, const int* in_sizes, int n_in,
                              void* d_out, int out_size, void* d_ws, size_t ws_size,
                              hipStream_t stream) {
    const float* x     = (const float*)d_in[0];
    const float* coeff = (const float*)d_in[1];
    float*  out = (float*)d_out;
    float2* pmm = (float2*)d_ws;               // NB1 float2 = 16 KiB

    const int total = in_sizes[0];             // 67,108,864
    const int n4    = total / 4;
    const int C     = in_sizes[1] / BINS;      // 64
    const int NC    = out_size;                // 4096
    const int hw4   = total / NC / 4;          // 4096 float4 per (n,c)

    minmax_partial<<<NB1, BT, 0, stream>>>((const float4*)x, n4, pmm);
    hpool_main<<<NC, BT, 0, stream>>>(x, coeff, pmm, out, C, hw4, NC);
}